// Round 8
// baseline (335.554 us; speedup 1.0000x reference)
//
#include <hip/hip_runtime.h>
#include <hip/hip_bf16.h>
#include <hip/hip_cooperative_groups.h>
#include <cstdint>
#include <cstddef>

// B=2, L=2048, D_MODEL=1024, D_INNER=2048, D_STATE=16, D_CONV=4, DT_RANK=64
// M = B*L = 4096. All inputs/output fp32; internals bf16.
// R8: (1) cooperative fused scan (stage once, grid.sync between phases,
//     phase-C correction-only rescan via cumsum(dt)) with occupancy-checked
//     fallback to the R7 3-kernel path; (2) conv 4-row register window.

namespace cg = cooperative_groups;

typedef __bf16 bf16x8 __attribute__((ext_vector_type(8)));
typedef __bf16 bf16x4 __attribute__((ext_vector_type(4)));
typedef float f32x4 __attribute__((ext_vector_type(4)));
typedef unsigned int u32x4 __attribute__((ext_vector_type(4)));

#define LOG2E 1.44269504088896f

__device__ __forceinline__ bf16x8 cvt8(const float* __restrict__ p) {
    f32x4 a = *(const f32x4*)p;
    f32x4 b = *(const f32x4*)(p + 4);
    bf16x8 o;
    o[0] = (__bf16)a[0]; o[1] = (__bf16)a[1]; o[2] = (__bf16)a[2]; o[3] = (__bf16)a[3];
    o[4] = (__bf16)b[0]; o[5] = (__bf16)b[1]; o[6] = (__bf16)b[2]; o[7] = (__bf16)b[3];
    return o;
}

__device__ __forceinline__ void gll16(const __bf16* g, __bf16* l) {
    __builtin_amdgcn_global_load_lds(
        (const __attribute__((address_space(1))) void*)g,
        (__attribute__((address_space(3))) void*)l, 16, 0, 0);
}

__device__ __forceinline__ uint32_t packbf(__bf16 lo, __bf16 hi) {
    uint16_t a = __builtin_bit_cast(uint16_t, lo);
    uint16_t b = __builtin_bit_cast(uint16_t, hi);
    return (uint32_t)a | ((uint32_t)b << 16);
}
__device__ __forceinline__ float lo2f(uint32_t u) { return __builtin_bit_cast(float, u << 16); }
__device__ __forceinline__ float hi2f(uint32_t u) { return __builtin_bit_cast(float, u & 0xffff0000u); }
__device__ __forceinline__ uint32_t f2hi(float y, uint32_t u) {
    uint16_t yb = __builtin_bit_cast(uint16_t, (__bf16)y);
    return (u & 0xffffu) | ((uint32_t)yb << 16);
}

template<int CTRL>
__device__ __forceinline__ float qp_add(float v) {
    int r = __builtin_amdgcn_update_dpp(0, __builtin_bit_cast(int, v), CTRL, 0xF, 0xF, true);
    return v + __builtin_bit_cast(float, r);
}

// ---------------------------------------------------------------------------
// fused f32->bf16 convert + conv-weight transpose cwT[4][2048]
// ---------------------------------------------------------------------------
__global__ void cvt_all_kernel(const float* __restrict__ u,   __bf16* __restrict__ ub,
                               const float* __restrict__ wi,  __bf16* __restrict__ wib,
                               const float* __restrict__ wo,  __bf16* __restrict__ wob,
                               const float* __restrict__ wx,  __bf16* __restrict__ wxb,
                               const float* __restrict__ wdt, __bf16* __restrict__ wdtb,
                               const float* __restrict__ cw,  float* __restrict__ cwT) {
    int i = blockIdx.x * 256 + threadIdx.x;      // 0 .. 1352703
    if (i < 1351680) {
        const float* s; __bf16* d; int off;
        if (i < 524288)                { s = u;   d = ub;   off = i; }
        else if (i < 1048576)          { s = wi;  d = wib;  off = i - 524288; }
        else if (i < 1310720)          { s = wo;  d = wob;  off = i - 1048576; }
        else if (i < 1335296)          { s = wx;  d = wxb;  off = i - 1310720; }
        else                           { s = wdt; d = wdtb; off = i - 1335296; }
        *(bf16x8*)(d + (size_t)off * 8) = cvt8(s + (size_t)off * 8);
    } else {
        int off = (i - 1351680) * 8;
#pragma unroll
        for (int e = 0; e < 8; ++e) {
            int s = off + e;
            cwT[(s & 3) * 2048 + (s >> 2)] = cw[s];
        }
    }
}

// ---------------------------------------------------------------------------
// m97-style GEMM: C_bf16[M][ldc] = A[M][K] @ B[N][K]^T (bf16 in)
// ---------------------------------------------------------------------------
__global__ __launch_bounds__(256, 3) void gemm_async_bf(const __bf16* __restrict__ A,
                                                        const __bf16* __restrict__ Bw,
                                                        __bf16* __restrict__ C,
                                                        int K, int ldc) {
    __shared__ __bf16 As[128][32];
    __shared__ __bf16 Bs[128][32];
    const int tid = threadIdx.x, lane = tid & 63, wave = tid >> 6;
    const int m0 = blockIdx.x * 128, n0 = blockIdx.y * 128;
    const int wm = (wave >> 1) * 64, wn = (wave & 1) * 64;
    const int mrow = lane & 15, kq = (lane >> 4) * 8;
    const int sr = wave * 32 + (lane >> 2);
    const int sk = (lane & 3) * 8;
    const __bf16* Ag0 = A + (size_t)(m0 + sr) * K + sk;
    const __bf16* Ag1 = Ag0 + (size_t)16 * K;
    const __bf16* Bg0 = Bw + (size_t)(n0 + sr) * K + sk;
    const __bf16* Bg1 = Bg0 + (size_t)16 * K;
    __bf16* La0 = &As[wave * 32][0];
    __bf16* La1 = &As[wave * 32 + 16][0];
    __bf16* Lb0 = &Bs[wave * 32][0];
    __bf16* Lb1 = &Bs[wave * 32 + 16][0];
    f32x4 acc[4][4] = {};
    for (int k0 = 0; k0 < K; k0 += 32) {
        gll16(Ag0 + k0, La0);
        gll16(Ag1 + k0, La1);
        gll16(Bg0 + k0, Lb0);
        gll16(Bg1 + k0, Lb1);
        __syncthreads();
        bf16x8 af[4], bfr[4];
#pragma unroll
        for (int i = 0; i < 4; ++i) af[i]  = *(const bf16x8*)&As[wm + i * 16 + mrow][kq];
#pragma unroll
        for (int j = 0; j < 4; ++j) bfr[j] = *(const bf16x8*)&Bs[wn + j * 16 + mrow][kq];
#pragma unroll
        for (int i = 0; i < 4; ++i)
#pragma unroll
            for (int j = 0; j < 4; ++j)
                acc[i][j] = __builtin_amdgcn_mfma_f32_16x16x32_bf16(af[i], bfr[j], acc[i][j], 0, 0, 0);
        __syncthreads();
    }
    const int col = lane & 15;
    const int rb = (lane >> 4) * 4;
#pragma unroll
    for (int i = 0; i < 4; ++i)
#pragma unroll
        for (int j = 0; j < 4; ++j)
#pragma unroll
            for (int r = 0; r < 4; ++r)
                C[(size_t)(m0 + wm + i * 16 + rb + r) * ldc + n0 + wn + j * 16 + col] =
                    (__bf16)acc[i][j][r];
}

// ---------------------------------------------------------------------------
// gemm6 split-K: P[z][4096][1024], A/B row stride 2048. grid (32, 8, 2).
// ---------------------------------------------------------------------------
__global__ __launch_bounds__(256, 3) void gemm_splitk(const __bf16* __restrict__ A,
                                                      const __bf16* __restrict__ Bw,
                                                      float* __restrict__ P) {
    __shared__ __bf16 As[128][32];
    __shared__ __bf16 Bs[128][32];
    const int tid = threadIdx.x, lane = tid & 63, wave = tid >> 6;
    const int m0 = blockIdx.x * 128, n0 = blockIdx.y * 128;
    const int kz = blockIdx.z * 1024;
    const int wm = (wave >> 1) * 64, wn = (wave & 1) * 64;
    const int mrow = lane & 15, kq = (lane >> 4) * 8;
    const int sr = wave * 32 + (lane >> 2);
    const int sk = (lane & 3) * 8;
    const __bf16* Ag0 = A + (size_t)(m0 + sr) * 2048 + kz + sk;
    const __bf16* Ag1 = Ag0 + (size_t)16 * 2048;
    const __bf16* Bg0 = Bw + (size_t)(n0 + sr) * 2048 + kz + sk;
    const __bf16* Bg1 = Bg0 + (size_t)16 * 2048;
    __bf16* La0 = &As[wave * 32][0];
    __bf16* La1 = &As[wave * 32 + 16][0];
    __bf16* Lb0 = &Bs[wave * 32][0];
    __bf16* Lb1 = &Bs[wave * 32 + 16][0];
    f32x4 acc[4][4] = {};
    for (int k0 = 0; k0 < 1024; k0 += 32) {
        gll16(Ag0 + k0, La0);
        gll16(Ag1 + k0, La1);
        gll16(Bg0 + k0, Lb0);
        gll16(Bg1 + k0, Lb1);
        __syncthreads();
        bf16x8 af[4], bfr[4];
#pragma unroll
        for (int i = 0; i < 4; ++i) af[i]  = *(const bf16x8*)&As[wm + i * 16 + mrow][kq];
#pragma unroll
        for (int j = 0; j < 4; ++j) bfr[j] = *(const bf16x8*)&Bs[wn + j * 16 + mrow][kq];
#pragma unroll
        for (int i = 0; i < 4; ++i)
#pragma unroll
            for (int j = 0; j < 4; ++j)
                acc[i][j] = __builtin_amdgcn_mfma_f32_16x16x32_bf16(af[i], bfr[j], acc[i][j], 0, 0, 0);
        __syncthreads();
    }
    const int col = lane & 15;
    const int rb = (lane >> 4) * 4;
    float* Pz = P + (size_t)blockIdx.z * 4096 * 1024;
#pragma unroll
    for (int i = 0; i < 4; ++i)
#pragma unroll
        for (int j = 0; j < 4; ++j)
#pragma unroll
            for (int r = 0; r < 4; ++r)
                Pz[(size_t)(m0 + wm + i * 16 + rb + r) * 1024 + n0 + wn + j * 16 + col] =
                    acc[i][j][r];
}

__global__ void add2_kernel(const float* __restrict__ P, float* __restrict__ out) {
    int i = blockIdx.x * 256 + threadIdx.x;
    f32x4 a = *(const f32x4*)(P + (size_t)i * 4);
    f32x4 b = *(const f32x4*)(P + (size_t)4096 * 1024 + (size_t)i * 4);
    *(f32x4*)(out + (size_t)i * 4) = a + b;
}

// ---------------------------------------------------------------------------
// Causal depthwise conv (K=4) + SiLU. 4 rows/block, rolling register window.
// grid 1024 x 256 threads (8 d-channels each).
// ---------------------------------------------------------------------------
__global__ void conv_silu_kernel(const __bf16* __restrict__ xz,
                                 const float* __restrict__ cwT,
                                 const float* __restrict__ cb,
                                 __bf16* __restrict__ x) {
    const int r0 = blockIdx.x * 4;
    const int d = threadIdx.x * 8;
    const bool first = (r0 & 2047) == 0;

    f32x4 w0[4], w1[4];
#pragma unroll
    for (int k = 0; k < 4; ++k) {
        w0[k] = *(const f32x4*)(cwT + k * 2048 + d);
        w1[k] = *(const f32x4*)(cwT + k * 2048 + d + 4);
    }
    f32x4 b0 = *(const f32x4*)(cb + d);
    f32x4 b1 = *(const f32x4*)(cb + d + 4);

    bf16x8 win[4];
#pragma unroll
    for (int i = 0; i < 3; ++i) {
        if (first) {
#pragma unroll
            for (int k = 0; k < 8; ++k) win[i][k] = (__bf16)0.f;
        } else {
            win[i] = *(const bf16x8*)(xz + (size_t)(r0 - 3 + i) * 4096 + d);
        }
    }
#pragma unroll
    for (int rr = 0; rr < 4; ++rr) {
        win[(rr + 3) & 3] = *(const bf16x8*)(xz + (size_t)(r0 + rr) * 4096 + d);
        float acc[8];
#pragma unroll
        for (int i = 0; i < 4; ++i) { acc[i] = b0[i]; acc[4 + i] = b1[i]; }
#pragma unroll
        for (int k = 0; k < 4; ++k) {        // tap k multiplies row r0+rr-3+k
            bf16x8 v = win[(rr + k) & 3];
#pragma unroll
            for (int i = 0; i < 4; ++i) {
                acc[i]     = fmaf((float)v[i],     w0[k][i], acc[i]);
                acc[4 + i] = fmaf((float)v[4 + i], w1[k][i], acc[4 + i]);
            }
        }
        bf16x8 o;
#pragma unroll
        for (int i = 0; i < 8; ++i) {
            float s = acc[i];
            s = s / (1.f + __expf(-s));
            o[i] = (__bf16)s;
        }
        *(bf16x8*)(x + (size_t)(r0 + rr) * 2048 + d) = o;
    }
}

// ---------------------------------------------------------------------------
// gemm_xp split-K: P[ks][4096][96] = x[:, ks*256:+256] @ Wx^T
// ---------------------------------------------------------------------------
__global__ __launch_bounds__(256, 2) void gemm_xp_split(const __bf16* __restrict__ A,
                                                        const __bf16* __restrict__ Bw,
                                                        float* __restrict__ P) {
    __shared__ __bf16 As[64][64];
    __shared__ __bf16 Bs[96][64];
    const int tid = threadIdx.x;
    const int lane = tid & 63;
    const int wave = tid >> 6;
    const int m0 = blockIdx.x * 64;
    const int kb = blockIdx.y * 256;
    const int mrow = lane & 15;
    const int kq = (lane >> 4) * 8;

    f32x4 acc[6] = {};

    for (int k0 = kb; k0 < kb + 256; k0 += 64) {
#pragma unroll
        for (int r = 0; r < 2; ++r) {
            int e = r * 256 + tid;
            int row = e >> 3, kc = e & 7;
            *(bf16x8*)&As[row][kc * 8] =
                *(const bf16x8*)(A + (size_t)(m0 + row) * 2048 + k0 + kc * 8);
        }
#pragma unroll
        for (int r = 0; r < 3; ++r) {
            int e = r * 256 + tid;
            int row = e >> 3, kc = e & 7;
            *(bf16x8*)&Bs[row][kc * 8] =
                *(const bf16x8*)(Bw + (size_t)row * 2048 + k0 + kc * 8);
        }
        __syncthreads();
#pragma unroll
        for (int kc = 0; kc < 2; ++kc) {
            bf16x8 af = *(const bf16x8*)&As[wave * 16 + mrow][kc * 32 + kq];
#pragma unroll
            for (int j = 0; j < 6; ++j) {
                bf16x8 bfr = *(const bf16x8*)&Bs[j * 16 + mrow][kc * 32 + kq];
                acc[j] = __builtin_amdgcn_mfma_f32_16x16x32_bf16(af, bfr, acc[j], 0, 0, 0);
            }
        }
        __syncthreads();
    }
    const int col = lane & 15;
    const int rb = (lane >> 4) * 4;
    float* Pb = P + (size_t)blockIdx.y * 4096 * 96;
#pragma unroll
    for (int j = 0; j < 6; ++j)
#pragma unroll
        for (int r = 0; r < 4; ++r)
            Pb[(size_t)(m0 + wave * 16 + rb + r) * 96 + j * 16 + col] = acc[j][r];
}

__global__ void xp_reduce(const float* __restrict__ P, __bf16* __restrict__ xp) {
    int m = blockIdx.x, c = threadIdx.x;
    if (c < 96) {
        float s = 0.f;
#pragma unroll
        for (int k = 0; k < 8; ++k) s += P[(size_t)k * 4096 * 96 + (size_t)m * 96 + c];
        xp[(size_t)m * 96 + c] = (__bf16)s;
    }
}

// ---------------------------------------------------------------------------
// dt = softplus(x_p[:, :64] @ W_dt^T + b_dt) -> bf16 into xz[:, :2048]
// ---------------------------------------------------------------------------
__global__ __launch_bounds__(256, 2) void gemm_dt(const __bf16* __restrict__ xp,
                                                  const __bf16* __restrict__ Wdt,
                                                  const float* __restrict__ bdt,
                                                  __bf16* __restrict__ dt) {
    const int tid = threadIdx.x;
    const int lane = tid & 63;
    const int wave = tid >> 6;
    const int m0 = blockIdx.x * 128 + (wave >> 1) * 64;
    const int n0 = blockIdx.y * 128 + (wave & 1) * 64;
    const int mrow = lane & 15;
    const int kq = (lane >> 4) * 8;

    f32x4 acc[4][4] = {};
#pragma unroll
    for (int kc = 0; kc < 2; ++kc) {
        bf16x8 af[4], bfr[4];
#pragma unroll
        for (int i = 0; i < 4; ++i)
            af[i] = *(const bf16x8*)(xp + (size_t)(m0 + i * 16 + mrow) * 96 + kc * 32 + kq);
#pragma unroll
        for (int j = 0; j < 4; ++j)
            bfr[j] = *(const bf16x8*)(Wdt + (size_t)(n0 + j * 16 + mrow) * 64 + kc * 32 + kq);
#pragma unroll
        for (int i = 0; i < 4; ++i)
#pragma unroll
            for (int j = 0; j < 4; ++j)
                acc[i][j] = __builtin_amdgcn_mfma_f32_16x16x32_bf16(af[i], bfr[j], acc[i][j], 0, 0, 0);
    }
    const int col = lane & 15;
    const int rb = (lane >> 4) * 4;
#pragma unroll
    for (int i = 0; i < 4; ++i)
#pragma unroll
        for (int j = 0; j < 4; ++j) {
            int cc = n0 + j * 16 + col;
            float bias = bdt[cc];
#pragma unroll
            for (int r = 0; r < 4; ++r) {
                float v = acc[i][j][r] + bias;
                float sp = (v > 20.f) ? v : log1pf(__expf(v));
                dt[(size_t)(m0 + i * 16 + rb + r) * 4096 + cc] = (__bf16)sp;
            }
        }
}

// ===========================================================================
// COOPERATIVE FUSED SCAN: 16 chunks x 128 steps, grid 1024 (2b x 16c x 32dt),
// 4 blocks/CU co-resident (LDS exactly 40 KB). Phases A/B/C with grid.sync().
// ===========================================================================
__global__ __launch_bounds__(256, 4) void scan_fused(const __bf16* __restrict__ xz,
                                                     __bf16* __restrict__ xq,
                                                     const __bf16* __restrict__ xp,
                                                     const float* __restrict__ A_log,
                                                     const float* __restrict__ Dp,
                                                     float* __restrict__ h_end,
                                                     float* __restrict__ dtsum,
                                                     float* __restrict__ h_in) {
    __shared__ uint32_t s_dtx[128][64];   // (x<<16)|dt -> (ybf16<<16)|dt -> f32 y
    __shared__ uint32_t s_BC[128][16];    // (C<<16)|B
    const int tid = threadIdx.x;
    const int bi = blockIdx.x;
    const int b = bi >> 9, c = (bi >> 5) & 15, d0 = (bi & 31) * 64;
    const int row0 = b * 2048 + c * 128;

    const int lane = tid & 63, wave = tid >> 6;
    const int dcol = wave * 16 + (lane >> 2);
    const int d = d0 + dcol;
    const int ng = lane & 3;
    f32x4 Al = *(const f32x4*)(A_log + (size_t)d * 16 + ng * 4);
    float Adn2[4];
#pragma unroll
    for (int j = 0; j < 4; ++j) Adn2[j] = -__expf(Al[j]) * LOG2E;
    const float Dd = Dp[d];

    // ---- stage dt/x and B/C ----
#pragma unroll
    for (int i = 0; i < 8; ++i) {
        int w = i * 256 + tid;
        int t = w >> 4, g = (w & 15) * 4;
        size_t r = (size_t)(row0 + t);
        bf16x4 dt4 = *(const bf16x4*)(xz + r * 4096 + d0 + g);
        bf16x4 x4  = *(const bf16x4*)(xq + r * 2048 + d0 + g);
        u32x4 o;
#pragma unroll
        for (int k = 0; k < 4; ++k) o[k] = packbf(dt4[k], x4[k]);
        *(u32x4*)&s_dtx[t][g] = o;
    }
#pragma unroll
    for (int i = 0; i < 2; ++i) {
        int w = i * 256 + tid;
        int t = w >> 2, g = (w & 3) * 4;
        bf16x4 B4 = *(const bf16x4*)(xp + (size_t)(row0 + t) * 96 + 64 + g);
        bf16x4 C4 = *(const bf16x4*)(xp + (size_t)(row0 + t) * 96 + 80 + g);
        u32x4 o;
#pragma unroll
        for (int k = 0; k < 4; ++k) o[k] = packbf(B4[k], C4[k]);
        *(u32x4*)&s_BC[t][g] = o;
    }
    __syncthreads();

    // ---- phase A: local scan from h=0; emit y_local into slot high bits ----
    {
        float h[4] = {0.f, 0.f, 0.f, 0.f};
        float ds = 0.f;
#pragma unroll 4
        for (int t = 0; t < 128; ++t) {
            uint32_t u = s_dtx[t][dcol];
            float dt = lo2f(u), x = hi2f(u);
            u32x4 bc = *(const u32x4*)&s_BC[t][ng * 4];
            float p = dt * x;
            float cs;
#pragma unroll
            for (int j = 0; j < 4; ++j) {
                float Bv = lo2f(bc[j]), Cv = hi2f(bc[j]);
                float dA = exp2f(dt * Adn2[j]);
                h[j] = fmaf(dA, h[j], p * Bv);
                cs = (j == 0) ? h[0] * Cv : fmaf(h[j], Cv, cs);
            }
            ds += dt;
            cs = qp_add<0xB1>(cs);
            cs = qp_add<0x4E>(cs);
            if (ng == 0) s_dtx[t][dcol] = f2hi(fmaf(Dd, x, cs), u);
        }
        size_t base = (size_t)(b * 16 + c) * 2048 + d;
        f32x4 hv = {h[0], h[1], h[2], h[3]};
        *(f32x4*)(h_end + base * 16 + ng * 4) = hv;
        if (ng == 0) dtsum[base] = ds;
    }

    cg::this_grid().sync();

    // ---- phase B: 16-chunk prefix (blocks 0..255 only) ----
    if (bi < 256) {
        int idx = bi * 256 + tid;
        int bb = idx >> 15, rem = idx & 32767;
        int dd = rem >> 4;
        float Adn = -__expf(A_log[rem]);
        float h = 0.f;
#pragma unroll
        for (int cc = 0; cc < 16; ++cc) {
            size_t base = ((size_t)(bb * 16 + cc) << 15) + rem;
            h_in[base] = h;
            float P = __expf(Adn * dtsum[((size_t)(bb * 16 + cc) << 11) + dd]);
            h = fmaf(P, h, h_end[base]);
        }
    }

    cg::this_grid().sync();

    // ---- phase C: correction y = y_local + sum_n C*exp(A*Sd)*h_in ----
    {
        f32x4 hin = *(const f32x4*)(h_in + ((size_t)(b * 16 + c) * 2048 + d) * 16 + ng * 4);
        float Sd = 0.f;
#pragma unroll 4
        for (int t = 0; t < 128; ++t) {
            uint32_t u = s_dtx[t][dcol];
            float dt = lo2f(u);
            Sd += dt;
            u32x4 bc = *(const u32x4*)&s_BC[t][ng * 4];
            float corr;
#pragma unroll
            for (int j = 0; j < 4; ++j) {
                float Cv = hi2f(bc[j]);
                float e = exp2f(Sd * Adn2[j]);
                corr = (j == 0) ? e * hin[0] * Cv : fmaf(e * hin[j], Cv, corr);
            }
            corr = qp_add<0xB1>(corr);
            corr = qp_add<0x4E>(corr);
            if (ng == 0) {
                float yraw = hi2f(u) + corr;
                s_dtx[t][dcol] = __builtin_bit_cast(uint32_t, yraw);
            }
        }
    }
    __syncthreads();

    // ---- store: y = yraw * silu(z), coalesced ----
#pragma unroll
    for (int i = 0; i < 8; ++i) {
        int w = i * 256 + tid;
        int t = w >> 4, g = (w & 15) * 4;
        u32x4 yv = *(const u32x4*)&s_dtx[t][g];
        bf16x4 z4 = *(const bf16x4*)(xz + (size_t)(row0 + t) * 4096 + 2048 + d0 + g);
        bf16x4 o;
#pragma unroll
        for (int k = 0; k < 4; ++k) {
            float zv = (float)z4[k];
            float yv_f = __builtin_bit_cast(float, yv[k]);
            o[k] = (__bf16)(yv_f * (zv / (1.f + __expf(-zv))));
        }
        *(bf16x4*)(xq + (size_t)(row0 + t) * 2048 + d0 + g) = o;
    }
}

// ===========================================================================
// Fallback 3-kernel scan (R7): 32 chunks x 64 steps
// ===========================================================================
__global__ __launch_bounds__(256, 6) void scan_p1(const __bf16* __restrict__ xz,
                                                  const __bf16* __restrict__ xq,
                                                  const __bf16* __restrict__ xp,
                                                  const float* __restrict__ A_log,
                                                  float* __restrict__ h_end,
                                                  float* __restrict__ dtsum) {
    __shared__ uint32_t s_dtx[64][64];
    __shared__ __bf16 s_B[64][16];
    const int tid = threadIdx.x;
    const int bi = blockIdx.x;
    const int b = bi >> 10, c = (bi >> 5) & 31, d0 = (bi & 31) * 64;
    const int row0 = b * 2048 + c * 64;

    const int lane = tid & 63, wave = tid >> 6;
    const int dcol = wave * 16 + (lane >> 2);
    const int d = d0 + dcol;
    const int ng = lane & 3;
    f32x4 Al = *(const f32x4*)(A_log + (size_t)d * 16 + ng * 4);
    float Adn2[4];
#pragma unroll
    for (int j = 0; j < 4; ++j) Adn2[j] = -__expf(Al[j]) * LOG2E;

    {
        int t = tid >> 2, g = (tid & 3) * 4;
        *(bf16x4*)&s_B[t][g] = *(const bf16x4*)(xp + (size_t)(row0 + t) * 96 + 64 + g);
    }
#pragma unroll
    for (int i = 0; i < 4; ++i) {
        int w = i * 256 + tid;
        int t = w >> 4, g = (w & 15) * 4;
        size_t r = (size_t)(row0 + t);
        bf16x4 dt4 = *(const bf16x4*)(xz + r * 4096 + d0 + g);
        bf16x4 x4  = *(const bf16x4*)(xq + r * 2048 + d0 + g);
        u32x4 o;
#pragma unroll
        for (int k = 0; k < 4; ++k) o[k] = packbf(dt4[k], x4[k]);
        *(u32x4*)&s_dtx[t][g] = o;
    }
    __syncthreads();

    float h[4] = {0.f, 0.f, 0.f, 0.f};
    float ds = 0.f;
#pragma unroll 8
    for (int t = 0; t < 64; ++t) {
        uint32_t u = s_dtx[t][dcol];
        float dt = lo2f(u), x = hi2f(u);
        bf16x4 B4 = *(const bf16x4*)&s_B[t][ng * 4];
        float p = dt * x;
#pragma unroll
        for (int j = 0; j < 4; ++j) {
            float dA = exp2f(dt * Adn2[j]);
            h[j] = fmaf(dA, h[j], p * (float)B4[j]);
        }
        ds += dt;
    }
    size_t base = (size_t)(b * 32 + c) * 2048 + d;
    f32x4 hv = {h[0], h[1], h[2], h[3]};
    *(f32x4*)(h_end + base * 16 + ng * 4) = hv;
    if (ng == 0) dtsum[base] = ds;
}

__global__ __launch_bounds__(256) void scan_p2(const float* __restrict__ A_log,
                                               const float* __restrict__ dtsum,
                                               const float* __restrict__ h_end,
                                               float* __restrict__ h_in) {
    int idx = blockIdx.x * 256 + threadIdx.x;
    int b = idx >> 15, rem = idx & 32767;
    int d = rem >> 4;
    float Adn = -__expf(A_log[rem]);
    float h = 0.f;
#pragma unroll
    for (int c = 0; c < 32; ++c) {
        size_t base = ((size_t)(b * 32 + c) << 15) + rem;
        h_in[base] = h;
        float P = __expf(Adn * dtsum[((size_t)(b * 32 + c) << 11) + d]);
        h = fmaf(P, h, h_end[base]);
    }
}

__global__ __launch_bounds__(256, 4) void scan_p3(const __bf16* __restrict__ xz,
                                                  __bf16* __restrict__ xq,
                                                  const __bf16* __restrict__ xp,
                                                  const float* __restrict__ A_log,
                                                  const float* __restrict__ Dp,
                                                  const float* __restrict__ h_in) {
    __shared__ uint32_t s_dtx[64][64];
    __shared__ uint32_t s_BC[64][16];
    __shared__ __bf16 s_y[64][64];
    const int tid = threadIdx.x;
    const int bi = blockIdx.x;
    const int b = bi >> 10, c = (bi >> 5) & 31, d0 = (bi & 31) * 64;
    const int row0 = b * 2048 + c * 64;

    const int lane = tid & 63, wave = tid >> 6;
    const int dcol = wave * 16 + (lane >> 2);
    const int d = d0 + dcol;
    const int ng = lane & 3;
    f32x4 Al = *(const f32x4*)(A_log + (size_t)d * 16 + ng * 4);
    float Adn2[4];
#pragma unroll
    for (int j = 0; j < 4; ++j) Adn2[j] = -__expf(Al[j]) * LOG2E;
    const float Dd = Dp[d];
    f32x4 h = *(const f32x4*)(h_in + ((size_t)(b * 32 + c) * 2048 + d) * 16 + ng * 4);

    {
        int t = tid >> 2, g = (tid & 3) * 4;
        bf16x4 B4 = *(const bf16x4*)(xp + (size_t)(row0 + t) * 96 + 64 + g);
        bf16x4 C4 = *(const bf16x4*)(xp + (size_t)(row0 + t) * 96 + 80 + g);
        u32x4 o;
#pragma unroll
        for (int k = 0; k < 4; ++k) o[k] = packbf(B4[k], C4[k]);
        *(u32x4*)&s_BC[t][g] = o;
    }
#pragma unroll
    for (int i = 0; i < 4; ++i) {
        int w = i * 256 + tid;
        int t = w >> 4, g = (w & 15) * 4;
        size_t r = (size_t)(row0 + t);
        bf16x4 dt4 = *(const bf16x4*)(xz + r * 4096 + d0 + g);
        bf16x4 x4  = *(const bf16x4*)(xq + r * 2048 + d0 + g);
        u32x4 o;
#pragma unroll
        for (int k = 0; k < 4; ++k) o[k] = packbf(dt4[k], x4[k]);
        *(u32x4*)&s_dtx[t][g] = o;
    }
    __syncthreads();

#pragma unroll 8
    for (int t = 0; t < 64; ++t) {
        uint32_t u = s_dtx[t][dcol];
        float dt = lo2f(u), x = hi2f(u);
        u32x4 bc = *(const u32x4*)&s_BC[t][ng * 4];
        float p = dt * x;
        float cs;
#pragma unroll
        for (int j = 0; j < 4; ++j) {
            float Bv = lo2f(bc[j]), Cv = hi2f(bc[j]);
            float dA = exp2f(dt * Adn2[j]);
            h[j] = fmaf(dA, h[j], p * Bv);
            cs = (j == 0) ? h[0] * Cv : fmaf(h[j], Cv, cs);
        }
        cs = qp_add<0xB1>(cs);
        cs = qp_add<0x4E>(cs);
        if (ng == 0) s_y[t][dcol] = (__bf16)fmaf(Dd, x, cs);
    }
    __syncthreads();
#pragma unroll
    for (int i = 0; i < 2; ++i) {
        int w = i * 256 + tid;
        int t = w >> 3, g = (w & 7) * 8;
        bf16x8 z8 = *(const bf16x8*)(xz + (size_t)(row0 + t) * 4096 + 2048 + d0 + g);
        bf16x8 y8 = *(bf16x8*)&s_y[t][g];
        bf16x8 o;
#pragma unroll
        for (int k = 0; k < 8; ++k) {
            float zv = (float)z8[k];
            float yv = (float)y8[k] * (zv / (1.f + __expf(-zv)));
            o[k] = (__bf16)yv;
        }
        *(bf16x8*)(xq + (size_t)(row0 + t) * 2048 + d0 + g) = o;
    }
}

// ---------------------------------------------------------------------------
extern "C" void kernel_launch(void* const* d_in, const int* in_sizes, int n_in,
                              void* d_out, int out_size, void* d_ws, size_t ws_size,
                              hipStream_t stream) {
    const float* u      = (const float*)d_in[0];
    const float* W_in   = (const float*)d_in[1];
    const float* W_out  = (const float*)d_in[2];
    const float* conv_w = (const float*)d_in[3];
    const float* conv_b = (const float*)d_in[4];
    const float* W_x    = (const float*)d_in[5];
    const float* W_dt   = (const float*)d_in[6];
    const float* b_dt   = (const float*)d_in[7];
    const float* A_log  = (const float*)d_in[8];
    const float* D_p    = (const float*)d_in[9];
    float* out = (float*)d_out;

    // ws (bf16), ~61.4 MB:
    __bf16* xz   = (__bf16*)d_ws;                   // [4096][4096]: x_in->dt | z; then gemm6 f32 partials
    __bf16* xq   = xz  + (size_t)4096 * 4096;       // [4096][2048]: x -> y
    __bf16* xp   = xq  + (size_t)4096 * 2048;       // [4096][96]
    __bf16* Wib  = xp  + (size_t)4096 * 96;         // W_in bf16; after gemm1: dtsum f32
    __bf16* Wob  = Wib + (size_t)4096 * 1024;       // W_out bf16 [1024][2048]
    __bf16* Wxb  = Wob + (size_t)1024 * 2048;       // W_x   bf16 [96][2048]
    __bf16* Wdtb = Wxb + (size_t)96 * 2048;         // W_dt  bf16 [2048][64]

    // d_out as scratch (16.78 MB), lifetimes disjoint:
    __bf16* ub    = (__bf16*)d_out;                 // u bf16, dead after gemm1
    float* xpart  = (float*)d_out;                  // [8][4096][96] f32, dead after xp_reduce
    float* h_end  = (float*)d_out;                  // up to 8.39MB, written in scan phase A/p1
    float* h_in   = (float*)d_out + 2097152;        // 8.39MB @ 8.39MB
    float* cwT    = (float*)d_out + 3407872;        // 32KB @ 13.63MB; live cvt->conv only
    float* dtsum  = (float*)Wib;                    // 512 KB in dead Wib region
    float* gpart  = (float*)xz;                     // [2][4096][1024] f32, after scan

    cvt_all_kernel<<<5284, 256, 0, stream>>>(u, ub, W_in, Wib, W_out, Wob,
                                             W_x, Wxb, W_dt, Wdtb, conv_w, cwT);

    // 1. xz = ub @ Wib^T
    gemm_async_bf<<<dim3(32, 32), 256, 0, stream>>>(ub, Wib, xz, 1024, 4096);
    // 2. x = silu(conv(x_in)), 4-row register window
    conv_silu_kernel<<<1024, 256, 0, stream>>>(xz, cwT, conv_b, xq);
    // 3. x_p split-K + reduce
    gemm_xp_split<<<dim3(64, 8), 256, 0, stream>>>(xq, Wxb, xpart);
    xp_reduce<<<4096, 128, 0, stream>>>(xpart, xp);
    // 4. dt -> xz[:, :2048]
    gemm_dt<<<dim3(32, 16), 256, 0, stream>>>(xp, Wdtb, b_dt, xz);

    // 5. scan: cooperative fused if 4 blocks/CU fit, else 3-kernel fallback
    int maxb = 0;
    hipError_t qerr = hipOccupancyMaxActiveBlocksPerMultiprocessor(&maxb, scan_fused, 256, 0);
    bool coop_ok = (qerr == hipSuccess) && (maxb >= 4);
    if (coop_ok) {
        const __bf16* xz_c = xz; __bf16* xq_c = xq; const __bf16* xp_c = xp;
        const float* al_c = A_log; const float* dp_c = D_p;
        float* he_c = h_end; float* ds_c = dtsum; float* hi_c = h_in;
        void* args[] = {&xz_c, &xq_c, &xp_c, &al_c, &dp_c, &he_c, &ds_c, &hi_c};
        hipError_t lerr = hipLaunchCooperativeKernel((const void*)scan_fused,
                                                     dim3(1024), dim3(256),
                                                     args, 0, stream);
        if (lerr != hipSuccess) coop_ok = false;
    }
    if (!coop_ok) {
        scan_p1<<<2048, 256, 0, stream>>>(xz, xq, xp, A_log, h_end, dtsum);
        scan_p2<<<256, 256, 0, stream>>>(A_log, dtsum, h_end, h_in);
        scan_p3<<<2048, 256, 0, stream>>>(xz, xq, xp, A_log, D_p, h_in);
    }

    // 6. out = y @ Wob^T split-K x2 + reduce
    gemm_splitk<<<dim3(32, 8, 2), 256, 0, stream>>>(xq, Wob, gpart);
    add2_kernel<<<4096, 256, 0, stream>>>(gpart, out);
}

// Round 10
// 305.289 us; speedup vs baseline: 1.0991x; 1.0991x over previous
//
#include <hip/hip_runtime.h>
#include <hip/hip_bf16.h>
#include <cstdint>
#include <cstddef>

// B=2, L=2048, D_MODEL=1024, D_INNER=2048, D_STATE=16, D_CONV=4, DT_RANK=64
// M = B*L = 4096. All inputs/output fp32; internals bf16.
// R10: fix R9 compile (__exp2f -> __expf/__logf, the HIP fast intrinsics).
//      Retains: coop-scan revert, gemm_dt 128x64 tiles + fast softplus.

typedef __bf16 bf16x8 __attribute__((ext_vector_type(8)));
typedef __bf16 bf16x4 __attribute__((ext_vector_type(4)));
typedef float f32x4 __attribute__((ext_vector_type(4)));
typedef unsigned int u32x4 __attribute__((ext_vector_type(4)));

#define LOG2E 1.44269504088896f

__device__ __forceinline__ bf16x8 cvt8(const float* __restrict__ p) {
    f32x4 a = *(const f32x4*)p;
    f32x4 b = *(const f32x4*)(p + 4);
    bf16x8 o;
    o[0] = (__bf16)a[0]; o[1] = (__bf16)a[1]; o[2] = (__bf16)a[2]; o[3] = (__bf16)a[3];
    o[4] = (__bf16)b[0]; o[5] = (__bf16)b[1]; o[6] = (__bf16)b[2]; o[7] = (__bf16)b[3];
    return o;
}

__device__ __forceinline__ void gll16(const __bf16* g, __bf16* l) {
    __builtin_amdgcn_global_load_lds(
        (const __attribute__((address_space(1))) void*)g,
        (__attribute__((address_space(3))) void*)l, 16, 0, 0);
}

__device__ __forceinline__ uint32_t packbf(__bf16 lo, __bf16 hi) {
    uint16_t a = __builtin_bit_cast(uint16_t, lo);
    uint16_t b = __builtin_bit_cast(uint16_t, hi);
    return (uint32_t)a | ((uint32_t)b << 16);
}
__device__ __forceinline__ float lo2f(uint32_t u) { return __builtin_bit_cast(float, u << 16); }
__device__ __forceinline__ float hi2f(uint32_t u) { return __builtin_bit_cast(float, u & 0xffff0000u); }

template<int CTRL>
__device__ __forceinline__ float qp_add(float v) {
    int r = __builtin_amdgcn_update_dpp(0, __builtin_bit_cast(int, v), CTRL, 0xF, 0xF, true);
    return v + __builtin_bit_cast(float, r);
}

// fast softplus: log(1+e^v) via hw v_exp/v_log (HIP __expf/__logf)
__device__ __forceinline__ float softplus_fast(float v) {
    float sp = __logf(1.f + __expf(v));
    return (v > 15.f) ? v : sp;
}

// ---------------------------------------------------------------------------
// fused f32->bf16 convert + conv-weight transpose cwT[4][2048]
// ---------------------------------------------------------------------------
__global__ void cvt_all_kernel(const float* __restrict__ u,   __bf16* __restrict__ ub,
                               const float* __restrict__ wi,  __bf16* __restrict__ wib,
                               const float* __restrict__ wo,  __bf16* __restrict__ wob,
                               const float* __restrict__ wx,  __bf16* __restrict__ wxb,
                               const float* __restrict__ wdt, __bf16* __restrict__ wdtb,
                               const float* __restrict__ cw,  float* __restrict__ cwT) {
    int i = blockIdx.x * 256 + threadIdx.x;      // 0 .. 1352703
    if (i < 1351680) {
        const float* s; __bf16* d; int off;
        if (i < 524288)                { s = u;   d = ub;   off = i; }
        else if (i < 1048576)          { s = wi;  d = wib;  off = i - 524288; }
        else if (i < 1310720)          { s = wo;  d = wob;  off = i - 1048576; }
        else if (i < 1335296)          { s = wx;  d = wxb;  off = i - 1310720; }
        else                           { s = wdt; d = wdtb; off = i - 1335296; }
        *(bf16x8*)(d + (size_t)off * 8) = cvt8(s + (size_t)off * 8);
    } else {
        int off = (i - 1351680) * 8;
#pragma unroll
        for (int e = 0; e < 8; ++e) {
            int s = off + e;
            cwT[(s & 3) * 2048 + (s >> 2)] = cw[s];
        }
    }
}

// ---------------------------------------------------------------------------
// m97-style GEMM: C_bf16[M][ldc] = A[M][K] @ B[N][K]^T (bf16 in)
// ---------------------------------------------------------------------------
__global__ __launch_bounds__(256, 3) void gemm_async_bf(const __bf16* __restrict__ A,
                                                        const __bf16* __restrict__ Bw,
                                                        __bf16* __restrict__ C,
                                                        int K, int ldc) {
    __shared__ __bf16 As[128][32];
    __shared__ __bf16 Bs[128][32];
    const int tid = threadIdx.x, lane = tid & 63, wave = tid >> 6;
    const int m0 = blockIdx.x * 128, n0 = blockIdx.y * 128;
    const int wm = (wave >> 1) * 64, wn = (wave & 1) * 64;
    const int mrow = lane & 15, kq = (lane >> 4) * 8;
    const int sr = wave * 32 + (lane >> 2);
    const int sk = (lane & 3) * 8;
    const __bf16* Ag0 = A + (size_t)(m0 + sr) * K + sk;
    const __bf16* Ag1 = Ag0 + (size_t)16 * K;
    const __bf16* Bg0 = Bw + (size_t)(n0 + sr) * K + sk;
    const __bf16* Bg1 = Bg0 + (size_t)16 * K;
    __bf16* La0 = &As[wave * 32][0];
    __bf16* La1 = &As[wave * 32 + 16][0];
    __bf16* Lb0 = &Bs[wave * 32][0];
    __bf16* Lb1 = &Bs[wave * 32 + 16][0];
    f32x4 acc[4][4] = {};
    for (int k0 = 0; k0 < K; k0 += 32) {
        gll16(Ag0 + k0, La0);
        gll16(Ag1 + k0, La1);
        gll16(Bg0 + k0, Lb0);
        gll16(Bg1 + k0, Lb1);
        __syncthreads();
        bf16x8 af[4], bfr[4];
#pragma unroll
        for (int i = 0; i < 4; ++i) af[i]  = *(const bf16x8*)&As[wm + i * 16 + mrow][kq];
#pragma unroll
        for (int j = 0; j < 4; ++j) bfr[j] = *(const bf16x8*)&Bs[wn + j * 16 + mrow][kq];
#pragma unroll
        for (int i = 0; i < 4; ++i)
#pragma unroll
            for (int j = 0; j < 4; ++j)
                acc[i][j] = __builtin_amdgcn_mfma_f32_16x16x32_bf16(af[i], bfr[j], acc[i][j], 0, 0, 0);
        __syncthreads();
    }
    const int col = lane & 15;
    const int rb = (lane >> 4) * 4;
#pragma unroll
    for (int i = 0; i < 4; ++i)
#pragma unroll
        for (int j = 0; j < 4; ++j)
#pragma unroll
            for (int r = 0; r < 4; ++r)
                C[(size_t)(m0 + wm + i * 16 + rb + r) * ldc + n0 + wn + j * 16 + col] =
                    (__bf16)acc[i][j][r];
}

// ---------------------------------------------------------------------------
// gemm6 split-K: P[z][4096][1024], A/B row stride 2048. grid (32, 8, 2).
// ---------------------------------------------------------------------------
__global__ __launch_bounds__(256, 3) void gemm_splitk(const __bf16* __restrict__ A,
                                                      const __bf16* __restrict__ Bw,
                                                      float* __restrict__ P) {
    __shared__ __bf16 As[128][32];
    __shared__ __bf16 Bs[128][32];
    const int tid = threadIdx.x, lane = tid & 63, wave = tid >> 6;
    const int m0 = blockIdx.x * 128, n0 = blockIdx.y * 128;
    const int kz = blockIdx.z * 1024;
    const int wm = (wave >> 1) * 64, wn = (wave & 1) * 64;
    const int mrow = lane & 15, kq = (lane >> 4) * 8;
    const int sr = wave * 32 + (lane >> 2);
    const int sk = (lane & 3) * 8;
    const __bf16* Ag0 = A + (size_t)(m0 + sr) * 2048 + kz + sk;
    const __bf16* Ag1 = Ag0 + (size_t)16 * 2048;
    const __bf16* Bg0 = Bw + (size_t)(n0 + sr) * 2048 + kz + sk;
    const __bf16* Bg1 = Bg0 + (size_t)16 * 2048;
    __bf16* La0 = &As[wave * 32][0];
    __bf16* La1 = &As[wave * 32 + 16][0];
    __bf16* Lb0 = &Bs[wave * 32][0];
    __bf16* Lb1 = &Bs[wave * 32 + 16][0];
    f32x4 acc[4][4] = {};
    for (int k0 = 0; k0 < 1024; k0 += 32) {
        gll16(Ag0 + k0, La0);
        gll16(Ag1 + k0, La1);
        gll16(Bg0 + k0, Lb0);
        gll16(Bg1 + k0, Lb1);
        __syncthreads();
        bf16x8 af[4], bfr[4];
#pragma unroll
        for (int i = 0; i < 4; ++i) af[i]  = *(const bf16x8*)&As[wm + i * 16 + mrow][kq];
#pragma unroll
        for (int j = 0; j < 4; ++j) bfr[j] = *(const bf16x8*)&Bs[wn + j * 16 + mrow][kq];
#pragma unroll
        for (int i = 0; i < 4; ++i)
#pragma unroll
            for (int j = 0; j < 4; ++j)
                acc[i][j] = __builtin_amdgcn_mfma_f32_16x16x32_bf16(af[i], bfr[j], acc[i][j], 0, 0, 0);
        __syncthreads();
    }
    const int col = lane & 15;
    const int rb = (lane >> 4) * 4;
    float* Pz = P + (size_t)blockIdx.z * 4096 * 1024;
#pragma unroll
    for (int i = 0; i < 4; ++i)
#pragma unroll
        for (int j = 0; j < 4; ++j)
#pragma unroll
            for (int r = 0; r < 4; ++r)
                Pz[(size_t)(m0 + wm + i * 16 + rb + r) * 1024 + n0 + wn + j * 16 + col] =
                    acc[i][j][r];
}

__global__ void add2_kernel(const float* __restrict__ P, float* __restrict__ out) {
    int i = blockIdx.x * 256 + threadIdx.x;
    f32x4 a = *(const f32x4*)(P + (size_t)i * 4);
    f32x4 b = *(const f32x4*)(P + (size_t)4096 * 1024 + (size_t)i * 4);
    *(f32x4*)(out + (size_t)i * 4) = a + b;
}

// ---------------------------------------------------------------------------
// Causal depthwise conv (K=4) + SiLU. 4 rows/block, rolling register window.
// ---------------------------------------------------------------------------
__global__ void conv_silu_kernel(const __bf16* __restrict__ xz,
                                 const float* __restrict__ cwT,
                                 const float* __restrict__ cb,
                                 __bf16* __restrict__ x) {
    const int r0 = blockIdx.x * 4;
    const int d = threadIdx.x * 8;
    const bool first = (r0 & 2047) == 0;

    f32x4 w0[4], w1[4];
#pragma unroll
    for (int k = 0; k < 4; ++k) {
        w0[k] = *(const f32x4*)(cwT + k * 2048 + d);
        w1[k] = *(const f32x4*)(cwT + k * 2048 + d + 4);
    }
    f32x4 b0 = *(const f32x4*)(cb + d);
    f32x4 b1 = *(const f32x4*)(cb + d + 4);

    bf16x8 win[4];
#pragma unroll
    for (int i = 0; i < 3; ++i) {
        if (first) {
#pragma unroll
            for (int k = 0; k < 8; ++k) win[i][k] = (__bf16)0.f;
        } else {
            win[i] = *(const bf16x8*)(xz + (size_t)(r0 - 3 + i) * 4096 + d);
        }
    }
#pragma unroll
    for (int rr = 0; rr < 4; ++rr) {
        win[(rr + 3) & 3] = *(const bf16x8*)(xz + (size_t)(r0 + rr) * 4096 + d);
        float acc[8];
#pragma unroll
        for (int i = 0; i < 4; ++i) { acc[i] = b0[i]; acc[4 + i] = b1[i]; }
#pragma unroll
        for (int k = 0; k < 4; ++k) {
            bf16x8 v = win[(rr + k) & 3];
#pragma unroll
            for (int i = 0; i < 4; ++i) {
                acc[i]     = fmaf((float)v[i],     w0[k][i], acc[i]);
                acc[4 + i] = fmaf((float)v[4 + i], w1[k][i], acc[4 + i]);
            }
        }
        bf16x8 o;
#pragma unroll
        for (int i = 0; i < 8; ++i) {
            float s = acc[i];
            s = s / (1.f + __expf(-s));
            o[i] = (__bf16)s;
        }
        *(bf16x8*)(x + (size_t)(r0 + rr) * 2048 + d) = o;
    }
}

// ---------------------------------------------------------------------------
// gemm_xp split-K: P[ks][4096][96] = x[:, ks*256:+256] @ Wx^T
// ---------------------------------------------------------------------------
__global__ __launch_bounds__(256, 2) void gemm_xp_split(const __bf16* __restrict__ A,
                                                        const __bf16* __restrict__ Bw,
                                                        float* __restrict__ P) {
    __shared__ __bf16 As[64][64];
    __shared__ __bf16 Bs[96][64];
    const int tid = threadIdx.x;
    const int lane = tid & 63;
    const int wave = tid >> 6;
    const int m0 = blockIdx.x * 64;
    const int kb = blockIdx.y * 256;
    const int mrow = lane & 15;
    const int kq = (lane >> 4) * 8;

    f32x4 acc[6] = {};

    for (int k0 = kb; k0 < kb + 256; k0 += 64) {
#pragma unroll
        for (int r = 0; r < 2; ++r) {
            int e = r * 256 + tid;
            int row = e >> 3, kc = e & 7;
            *(bf16x8*)&As[row][kc * 8] =
                *(const bf16x8*)(A + (size_t)(m0 + row) * 2048 + k0 + kc * 8);
        }
#pragma unroll
        for (int r = 0; r < 3; ++r) {
            int e = r * 256 + tid;
            int row = e >> 3, kc = e & 7;
            *(bf16x8*)&Bs[row][kc * 8] =
                *(const bf16x8*)(Bw + (size_t)row * 2048 + k0 + kc * 8);
        }
        __syncthreads();
#pragma unroll
        for (int kc = 0; kc < 2; ++kc) {
            bf16x8 af = *(const bf16x8*)&As[wave * 16 + mrow][kc * 32 + kq];
#pragma unroll
            for (int j = 0; j < 6; ++j) {
                bf16x8 bfr = *(const bf16x8*)&Bs[j * 16 + mrow][kc * 32 + kq];
                acc[j] = __builtin_amdgcn_mfma_f32_16x16x32_bf16(af, bfr, acc[j], 0, 0, 0);
            }
        }
        __syncthreads();
    }
    const int col = lane & 15;
    const int rb = (lane >> 4) * 4;
    float* Pb = P + (size_t)blockIdx.y * 4096 * 96;
#pragma unroll
    for (int j = 0; j < 6; ++j)
#pragma unroll
        for (int r = 0; r < 4; ++r)
            Pb[(size_t)(m0 + wave * 16 + rb + r) * 96 + j * 16 + col] = acc[j][r];
}

__global__ void xp_reduce(const float* __restrict__ P, __bf16* __restrict__ xp) {
    int m = blockIdx.x, c = threadIdx.x;
    if (c < 96) {
        float s = 0.f;
#pragma unroll
        for (int k = 0; k < 8; ++k) s += P[(size_t)k * 4096 * 96 + (size_t)m * 96 + c];
        xp[(size_t)m * 96 + c] = (__bf16)s;
    }
}

// ---------------------------------------------------------------------------
// dt = softplus(x_p[:, :64] @ W_dt^T + b_dt) -> bf16 into xz[:, :2048].
// 128x64 tile, grid (32,32) = 1024 blocks = 4/CU; fast softplus.
// ---------------------------------------------------------------------------
__global__ __launch_bounds__(256, 4) void gemm_dt(const __bf16* __restrict__ xp,
                                                  const __bf16* __restrict__ Wdt,
                                                  const float* __restrict__ bdt,
                                                  __bf16* __restrict__ dt) {
    const int tid = threadIdx.x;
    const int lane = tid & 63;
    const int wave = tid >> 6;
    const int m0 = blockIdx.x * 128 + (wave >> 1) * 64;
    const int n0 = blockIdx.y * 64 + (wave & 1) * 32;
    const int mrow = lane & 15;
    const int kq = (lane >> 4) * 8;

    f32x4 acc[4][2] = {};
#pragma unroll
    for (int kc = 0; kc < 2; ++kc) {
        bf16x8 af[4], bfr[2];
#pragma unroll
        for (int i = 0; i < 4; ++i)
            af[i] = *(const bf16x8*)(xp + (size_t)(m0 + i * 16 + mrow) * 96 + kc * 32 + kq);
#pragma unroll
        for (int j = 0; j < 2; ++j)
            bfr[j] = *(const bf16x8*)(Wdt + (size_t)(n0 + j * 16 + mrow) * 64 + kc * 32 + kq);
#pragma unroll
        for (int i = 0; i < 4; ++i)
#pragma unroll
            for (int j = 0; j < 2; ++j)
                acc[i][j] = __builtin_amdgcn_mfma_f32_16x16x32_bf16(af[i], bfr[j], acc[i][j], 0, 0, 0);
    }
    const int col = lane & 15;
    const int rb = (lane >> 4) * 4;
#pragma unroll
    for (int i = 0; i < 4; ++i)
#pragma unroll
        for (int j = 0; j < 2; ++j) {
            int cc = n0 + j * 16 + col;
            float bias = bdt[cc];
#pragma unroll
            for (int r = 0; r < 4; ++r) {
                float v = acc[i][j][r] + bias;
                dt[(size_t)(m0 + i * 16 + rb + r) * 4096 + cc] = (__bf16)softplus_fast(v);
            }
        }
}

// ---------------------------------------------------------------------------
// Chunked scan: 32 chunks x 64 steps (R7-proven).
// ---------------------------------------------------------------------------
__global__ __launch_bounds__(256, 6) void scan_p1(const __bf16* __restrict__ xz,
                                                  const __bf16* __restrict__ xq,
                                                  const __bf16* __restrict__ xp,
                                                  const float* __restrict__ A_log,
                                                  float* __restrict__ h_end,
                                                  float* __restrict__ dtsum) {
    __shared__ uint32_t s_dtx[64][64];
    __shared__ __bf16 s_B[64][16];
    const int tid = threadIdx.x;
    const int bi = blockIdx.x;
    const int b = bi >> 10, c = (bi >> 5) & 31, d0 = (bi & 31) * 64;
    const int row0 = b * 2048 + c * 64;

    const int lane = tid & 63, wave = tid >> 6;
    const int dcol = wave * 16 + (lane >> 2);
    const int d = d0 + dcol;
    const int ng = lane & 3;
    f32x4 Al = *(const f32x4*)(A_log + (size_t)d * 16 + ng * 4);
    float Adn2[4];
#pragma unroll
    for (int j = 0; j < 4; ++j) Adn2[j] = -__expf(Al[j]) * LOG2E;

    {
        int t = tid >> 2, g = (tid & 3) * 4;
        *(bf16x4*)&s_B[t][g] = *(const bf16x4*)(xp + (size_t)(row0 + t) * 96 + 64 + g);
    }
#pragma unroll
    for (int i = 0; i < 4; ++i) {
        int w = i * 256 + tid;
        int t = w >> 4, g = (w & 15) * 4;
        size_t r = (size_t)(row0 + t);
        bf16x4 dt4 = *(const bf16x4*)(xz + r * 4096 + d0 + g);
        bf16x4 x4  = *(const bf16x4*)(xq + r * 2048 + d0 + g);
        u32x4 o;
#pragma unroll
        for (int k = 0; k < 4; ++k) o[k] = packbf(dt4[k], x4[k]);
        *(u32x4*)&s_dtx[t][g] = o;
    }
    __syncthreads();

    float h[4] = {0.f, 0.f, 0.f, 0.f};
    float ds = 0.f;
#pragma unroll 8
    for (int t = 0; t < 64; ++t) {
        uint32_t u = s_dtx[t][dcol];
        float dt = lo2f(u), x = hi2f(u);
        bf16x4 B4 = *(const bf16x4*)&s_B[t][ng * 4];
        float p = dt * x;
#pragma unroll
        for (int j = 0; j < 4; ++j) {
            float dA = exp2f(dt * Adn2[j]);
            h[j] = fmaf(dA, h[j], p * (float)B4[j]);
        }
        ds += dt;
    }
    size_t base = (size_t)(b * 32 + c) * 2048 + d;
    f32x4 hv = {h[0], h[1], h[2], h[3]};
    *(f32x4*)(h_end + base * 16 + ng * 4) = hv;
    if (ng == 0) dtsum[base] = ds;
}

__global__ __launch_bounds__(256) void scan_p2(const float* __restrict__ A_log,
                                               const float* __restrict__ dtsum,
                                               const float* __restrict__ h_end,
                                               float* __restrict__ h_in) {
    int idx = blockIdx.x * 256 + threadIdx.x;
    int b = idx >> 15, rem = idx & 32767;
    int d = rem >> 4;
    float Adn = -__expf(A_log[rem]);
    float h = 0.f;
#pragma unroll
    for (int c = 0; c < 32; ++c) {
        size_t base = ((size_t)(b * 32 + c) << 15) + rem;
        h_in[base] = h;
        float P = __expf(Adn * dtsum[((size_t)(b * 32 + c) << 11) + d]);
        h = fmaf(P, h, h_end[base]);
    }
}

__global__ __launch_bounds__(256, 4) void scan_p3(const __bf16* __restrict__ xz,
                                                  __bf16* __restrict__ xq,
                                                  const __bf16* __restrict__ xp,
                                                  const float* __restrict__ A_log,
                                                  const float* __restrict__ Dp,
                                                  const float* __restrict__ h_in) {
    __shared__ uint32_t s_dtx[64][64];
    __shared__ uint32_t s_BC[64][16];
    __shared__ __bf16 s_y[64][64];
    const int tid = threadIdx.x;
    const int bi = blockIdx.x;
    const int b = bi >> 10, c = (bi >> 5) & 31, d0 = (bi & 31) * 64;
    const int row0 = b * 2048 + c * 64;

    const int lane = tid & 63, wave = tid >> 6;
    const int dcol = wave * 16 + (lane >> 2);
    const int d = d0 + dcol;
    const int ng = lane & 3;
    f32x4 Al = *(const f32x4*)(A_log + (size_t)d * 16 + ng * 4);
    float Adn2[4];
#pragma unroll
    for (int j = 0; j < 4; ++j) Adn2[j] = -__expf(Al[j]) * LOG2E;
    const float Dd = Dp[d];
    f32x4 h = *(const f32x4*)(h_in + ((size_t)(b * 32 + c) * 2048 + d) * 16 + ng * 4);

    {
        int t = tid >> 2, g = (tid & 3) * 4;
        bf16x4 B4 = *(const bf16x4*)(xp + (size_t)(row0 + t) * 96 + 64 + g);
        bf16x4 C4 = *(const bf16x4*)(xp + (size_t)(row0 + t) * 96 + 80 + g);
        u32x4 o;
#pragma unroll
        for (int k = 0; k < 4; ++k) o[k] = packbf(B4[k], C4[k]);
        *(u32x4*)&s_BC[t][g] = o;
    }
#pragma unroll
    for (int i = 0; i < 4; ++i) {
        int w = i * 256 + tid;
        int t = w >> 4, g = (w & 15) * 4;
        size_t r = (size_t)(row0 + t);
        bf16x4 dt4 = *(const bf16x4*)(xz + r * 4096 + d0 + g);
        bf16x4 x4  = *(const bf16x4*)(xq + r * 2048 + d0 + g);
        u32x4 o;
#pragma unroll
        for (int k = 0; k < 4; ++k) o[k] = packbf(dt4[k], x4[k]);
        *(u32x4*)&s_dtx[t][g] = o;
    }
    __syncthreads();

#pragma unroll 8
    for (int t = 0; t < 64; ++t) {
        uint32_t u = s_dtx[t][dcol];
        float dt = lo2f(u), x = hi2f(u);
        u32x4 bc = *(const u32x4*)&s_BC[t][ng * 4];
        float p = dt * x;
        float cs;
#pragma unroll
        for (int j = 0; j < 4; ++j) {
            float Bv = lo2f(bc[j]), Cv = hi2f(bc[j]);
            float dA = exp2f(dt * Adn2[j]);
            h[j] = fmaf(dA, h[j], p * Bv);
            cs = (j == 0) ? h[0] * Cv : fmaf(h[j], Cv, cs);
        }
        cs = qp_add<0xB1>(cs);
        cs = qp_add<0x4E>(cs);
        if (ng == 0) s_y[t][dcol] = (__bf16)fmaf(Dd, x, cs);
    }
    __syncthreads();
#pragma unroll
    for (int i = 0; i < 2; ++i) {
        int w = i * 256 + tid;
        int t = w >> 3, g = (w & 7) * 8;
        bf16x8 z8 = *(const bf16x8*)(xz + (size_t)(row0 + t) * 4096 + 2048 + d0 + g);
        bf16x8 y8 = *(bf16x8*)&s_y[t][g];
        bf16x8 o;
#pragma unroll
        for (int k = 0; k < 8; ++k) {
            float zv = (float)z8[k];
            float yv = (float)y8[k] * (zv / (1.f + __expf(-zv)));
            o[k] = (__bf16)yv;
        }
        *(bf16x8*)(xq + (size_t)(row0 + t) * 2048 + d0 + g) = o;
    }
}

// ---------------------------------------------------------------------------
extern "C" void kernel_launch(void* const* d_in, const int* in_sizes, int n_in,
                              void* d_out, int out_size, void* d_ws, size_t ws_size,
                              hipStream_t stream) {
    const float* u      = (const float*)d_in[0];
    const float* W_in   = (const float*)d_in[1];
    const float* W_out  = (const float*)d_in[2];
    const float* conv_w = (const float*)d_in[3];
    const float* conv_b = (const float*)d_in[4];
    const float* W_x    = (const float*)d_in[5];
    const float* W_dt   = (const float*)d_in[6];
    const float* b_dt   = (const float*)d_in[7];
    const float* A_log  = (const float*)d_in[8];
    const float* D_p    = (const float*)d_in[9];
    float* out = (float*)d_out;

    // ws (bf16), ~61.4 MB:
    __bf16* xz   = (__bf16*)d_ws;                   // [4096][4096]: x_in->dt | z; then gemm6 f32 partials
    __bf16* xq   = xz  + (size_t)4096 * 4096;       // [4096][2048]: x -> y
    __bf16* xp   = xq  + (size_t)4096 * 2048;       // [4096][96]
    __bf16* Wib  = xp  + (size_t)4096 * 96;         // W_in bf16; after gemm1: dtsum f32
    __bf16* Wob  = Wib + (size_t)4096 * 1024;       // W_out bf16 [1024][2048]
    __bf16* Wxb  = Wob + (size_t)1024 * 2048;       // W_x   bf16 [96][2048]
    __bf16* Wdtb = Wxb + (size_t)96 * 2048;         // W_dt  bf16 [2048][64]

    // d_out as scratch (16.78 MB), lifetimes disjoint:
    __bf16* ub    = (__bf16*)d_out;                 // u bf16, dead after gemm1
    float* xpart  = (float*)d_out;                  // [8][4096][96] f32, dead after xp_reduce
    float* h_end  = (float*)d_out;                  // 8.39MB, written in p1
    float* h_in   = (float*)d_out + 2097152;        // 8.39MB @ 8.39MB, written in p2
    float* cwT    = (float*)d_out + 3407872;        // 32KB @ 13.63MB; live cvt->conv only
    float* dtsum  = (float*)Wib;                    // 512 KB in dead Wib region
    float* gpart  = (float*)xz;                     // [2][4096][1024] f32, after p3

    cvt_all_kernel<<<5284, 256, 0, stream>>>(u, ub, W_in, Wib, W_out, Wob,
                                             W_x, Wxb, W_dt, Wdtb, conv_w, cwT);

    // 1. xz = ub @ Wib^T
    gemm_async_bf<<<dim3(32, 32), 256, 0, stream>>>(ub, Wib, xz, 1024, 4096);
    // 2. x = silu(conv(x_in)), 4-row register window
    conv_silu_kernel<<<1024, 256, 0, stream>>>(xz, cwT, conv_b, xq);
    // 3. x_p split-K + reduce
    gemm_xp_split<<<dim3(64, 8), 256, 0, stream>>>(xq, Wxb, xpart);
    xp_reduce<<<4096, 128, 0, stream>>>(xpart, xp);
    // 4. dt -> xz[:, :2048]  (128x64 tiles, 1024 blocks, fast softplus)
    gemm_dt<<<dim3(32, 32), 256, 0, stream>>>(xp, Wdtb, b_dt, xz);
    // 5. chunked scan (32 x 64)
    scan_p1<<<2048, 256, 0, stream>>>(xz, xq, xp, A_log, h_end, dtsum);
    scan_p2<<<256, 256, 0, stream>>>(A_log, dtsum, h_end, h_in);
    scan_p3<<<2048, 256, 0, stream>>>(xz, xq, xp, A_log, D_p, h_in);
    // 6. out = y @ Wob^T split-K x2 + reduce
    gemm_splitk<<<dim3(32, 8, 2), 256, 0, stream>>>(xq, Wob, gpart);
    add2_kernel<<<4096, 256, 0, stream>>>(gpart, out);
}